// Round 10
// baseline (165.963 us; speedup 1.0000x reference)
//
#include <hip/hip_runtime.h>

#define B_ 2
#define S_ 2048
#define D_ 1024
#define H_ 16
#define DK_ 64
#define M_ (B_ * S_)   // 4096
#define N_ (3 * D_)    // 3072

typedef __bf16 bf16x8 __attribute__((ext_vector_type(8)));
typedef short s8vec __attribute__((ext_vector_type(8)));
typedef float f4vec __attribute__((ext_vector_type(4)));
typedef float f16vec __attribute__((ext_vector_type(16)));

static __device__ __forceinline__ ushort f2b(float f) {
  union { float f; unsigned u; } v; v.f = f;
  unsigned u = v.u;
  u += 0x7FFFu + ((u >> 16) & 1u);   // RNE to bf16
  return (ushort)(u >> 16);
}

static __device__ __forceinline__ unsigned pk2(float a, float b) {
#if __has_builtin(__builtin_amdgcn_cvt_pk_bf16_f32)
  typedef __bf16 b2 __attribute__((ext_vector_type(2)));
  b2 r = __builtin_amdgcn_cvt_pk_bf16_f32(a, b);
  return __builtin_bit_cast(unsigned, r);
#else
  return (unsigned)f2b(a) | ((unsigned)f2b(b) << 16);
#endif
}

static __device__ __forceinline__ float exp2f_fast(float x) {
#if __has_builtin(__builtin_amdgcn_exp2f)
  return __builtin_amdgcn_exp2f(x);
#else
  return __expf(x * 0.6931471805599453f);   // 2^x = e^(x ln2)
#endif
}

static __device__ __forceinline__ f4vec mfma16(s8vec a, s8vec b, f4vec c) {
  return __builtin_amdgcn_mfma_f32_16x16x32_bf16(
      __builtin_bit_cast(bf16x8, a), __builtin_bit_cast(bf16x8, b), c, 0, 0, 0);
}

static __device__ __forceinline__ f16vec mfma32(s8vec a, s8vec b, f16vec c) {
  return __builtin_amdgcn_mfma_f32_32x32x16_bf16(
      __builtin_bit_cast(bf16x8, a), __builtin_bit_cast(bf16x8, b), c, 0, 0, 0);
}

static __device__ __forceinline__ void gl_lds16(const ushort* g, ushort* l) {
  __builtin_amdgcn_global_load_lds(
      (const __attribute__((address_space(1))) unsigned*)g,
      (__attribute__((address_space(3))) unsigned*)l, 16, 0, 0);
}

// ---- fused input conversion: blocks [0,4096) convert x, [4096,4864) transpose W ----
// Wq (w==0) is pre-scaled by log2(e) so attn can use exp2 directly.
__global__ __launch_bounds__(256) void cvt_xw(const float* __restrict__ x,
                                              const float* __restrict__ Wq,
                                              const float* __restrict__ Wk,
                                              const float* __restrict__ Wv,
                                              ushort* __restrict__ xb,
                                              ushort* __restrict__ wbt) {
  __shared__ ushort T[64 * 72];
  const int t = threadIdx.x;
  if (blockIdx.x < 4096) {
    int i = blockIdx.x * 256 + t;
    float4 v = ((const float4*)x)[i];
    ushort4 o;
    o.x = f2b(v.x); o.y = f2b(v.y); o.z = f2b(v.z); o.w = f2b(v.w);
    ((ushort4*)xb)[i] = o;
    return;
  }
  const int r = blockIdx.x - 4096;                // 0..767
  const int w = r >> 8, h = (r >> 4) & 15, d0 = (r & 15) * 64;
  const float* W = (w == 0) ? Wq : (w == 1) ? Wk : Wv;
  const float sc = (w == 0) ? 1.4426950408889634f : 1.0f;
  const float* src = W + (size_t)h * 65536 + (size_t)d0 * 64;   // [64 d][64 k]
#pragma unroll
  for (int j = 0; j < 4; ++j) {
    int idx = j * 256 + t;
    int dr = idx >> 4, kc = (idx & 15) * 4;
    float4 v = *(const float4*)(src + dr * 64 + kc);
    T[(kc + 0) * 72 + dr] = f2b(v.x * sc);
    T[(kc + 1) * 72 + dr] = f2b(v.y * sc);
    T[(kc + 2) * 72 + dr] = f2b(v.z * sc);
    T[(kc + 3) * 72 + dr] = f2b(v.w * sc);
  }
  __syncthreads();
  const int kk = t >> 2, dcg = (t & 3) * 16;
  ushort* dst = wbt + ((size_t)w * 1024 + h * 64 + kk) * 1024 + d0 + dcg;
  *(s8vec*)dst       = *(const s8vec*)&T[kk * 72 + dcg];
  *(s8vec*)(dst + 8) = *(const s8vec*)&T[kk * 72 + dcg + 8];
}

// ---- fused QKV projection v11 (unchanged): 256x192 tile, BK=64, 512 thr,
// 2-phase double-buffered LDS, extended bank swizzle, 1 block/CU ----
__global__ __launch_bounds__(512) void proj_gemm(const ushort* __restrict__ xb,
                                                 const ushort* __restrict__ wbt,
                                                 ushort* __restrict__ qkv) {
  __shared__ __attribute__((aligned(16))) ushort As[2][256 * 64];
  __shared__ __attribute__((aligned(16))) ushort Bs[2][192 * 64];
  const int tid = threadIdx.x, wid = tid >> 6, lane = tid & 63;
  const int quad = lane >> 4, l15 = lane & 15;
  const int wm = wid & 1, wn = wid >> 1;
  const int m0 = blockIdx.x * 256, n0 = blockIdx.y * 192;

  f4vec acc[8][3];
#pragma unroll
  for (int mb = 0; mb < 8; mb++)
#pragma unroll
    for (int nb = 0; nb < 3; nb++)
#pragma unroll
      for (int i = 0; i < 4; i++) acc[mb][nb][i] = 0.f;

  const int sr = tid >> 3, sg = tid & 7;
  const int gk = sg ^ (sr & 7) ^ ((sr >> 3) & 7);
  const ushort* Ab = xb + (size_t)m0 * D_;
  const ushort* Bb = wbt + (size_t)n0 * D_;

#define PSTAGE(buf, k0_)                                                    \
  do {                                                                      \
    _Pragma("unroll")                                                       \
    for (int j = 0; j < 4; ++j)                                             \
      gl_lds16(Ab + (size_t)(j * 64 + sr) * D_ + (k0_) + gk * 8,            \
               &As[buf][(j * 64 + wid * 8) * 64]);                          \
    _Pragma("unroll")                                                       \
    for (int j = 0; j < 3; ++j)                                             \
      gl_lds16(Bb + (size_t)(j * 64 + sr) * D_ + (k0_) + gk * 8,            \
               &Bs[buf][(j * 64 + wid * 8) * 64]);                          \
  } while (0)

#define PCOMP(buf)                                                          \
  do {                                                                      \
    _Pragma("unroll")                                                       \
    for (int kb = 0; kb < 2; ++kb) {                                        \
      s8vec af[8], bf[3];                                                   \
      _Pragma("unroll")                                                     \
      for (int mb = 0; mb < 8; ++mb) {                                      \
        int m = wm * 128 + mb * 16 + l15;                                   \
        int gpos = (kb * 4 + quad) ^ (m & 7) ^ ((mb * 2 + (l15 >> 3)) & 7); \
        af[mb] = *(const s8vec*)&As[buf][m * 64 + gpos * 8];                \
      }                                                                     \
      _Pragma("unroll")                                                     \
      for (int nb = 0; nb < 3; ++nb) {                                      \
        int n = wn * 48 + nb * 16 + l15;                                    \
        int gpos = (kb * 4 + quad) ^ (n & 7) ^                              \
                   ((wn * 6 + nb * 2 + (l15 >> 3)) & 7);                    \
        bf[nb] = *(const s8vec*)&Bs[buf][n * 64 + gpos * 8];                \
      }                                                                     \
      _Pragma("unroll")                                                     \
      for (int mb = 0; mb < 8; ++mb)                                        \
        _Pragma("unroll")                                                   \
        for (int nb = 0; nb < 3; ++nb)                                      \
          acc[mb][nb] = mfma16(af[mb], bf[nb], acc[mb][nb]);                \
    }                                                                       \
  } while (0)

  PSTAGE(0, 0);
  __syncthreads();
  for (int t = 0; t < 15; ++t) {
    const int cur = t & 1;
    PSTAGE(cur ^ 1, (t + 1) * 64);
    PCOMP(cur);
    __syncthreads();
  }
  PCOMP(1);
#undef PSTAGE
#undef PCOMP

  const size_t per = (size_t)B_ * H_ * S_ * DK_;
  ushort* vt = qkv + 2 * per;
#pragma unroll
  for (int mb = 0; mb < 8; ++mb)
#pragma unroll
    for (int nb = 0; nb < 3; ++nb) {
      const int n1g = n0 + wn * 48 + nb * 16 + l15;
      const int w = n1g >> 10, n1 = n1g & 1023;
      if (w == 2) {
#pragma unroll
        for (int i = 0; i < 4; ++i) {
          int m = m0 + wm * 128 + mb * 16 + quad * 4 + i;
          int b = m >> 11, s = m & 2047;
          vt[((size_t)b * 1024 + n1) * S_ + s] = f2b(acc[mb][nb][i]);
        }
      } else {
#pragma unroll
        for (int i = 0; i < 4; ++i) {
          int m = m0 + wm * 128 + mb * 16 + quad * 4 + i;
          int b = m >> 11, s = m & 2047;
          qkv[(size_t)w * per + (((size_t)b * H_ + (n1 >> 6)) * S_ + s) * 64 + (n1 & 63)] =
              f2b(acc[mb][nb][i]);
        }
      }
    }
}

// ---- flash attention v12: v9's fat-wave geometry + v11's verified fixes.
// Q-tile 256, 512 thr = 8 waves (4 qgi x 2 kh), 64q x 64keys per wave,
// 32x32x16 MFMA. Grid (8,32) = 256 blocks = 1/CU, 2 waves/SIMD.
// Evidence: v9 (fat, 18% occ) 53.9 < v11 (thin, 31% occ) 58.2 — issue-bound,
// so amortize instructions over more q per wave. Fixes carried from v11:
// extended swizzle (row&7)^((row>>3)&7) (conflicts 4.2M->0 verified), direct
// gl_lds dbuf staging (1 barrier/tile, no reg-prefetch), XCD-chunked block
// swizzle (FETCH 70->12MB verified), setprio around MFMA. kh-halves merged in
// ONE round via 64 KB OM aliased over dead POOL.
__global__ __launch_bounds__(512) void attn(const ushort* __restrict__ qg,
                                            const ushort* __restrict__ kg,
                                            const ushort* __restrict__ vtg,
                                            float* __restrict__ out) {
  // POOL[buf]: Ks 128x64 @0, Vt [2 kh][64 dv][64 k] @8192  (32 KB per buf)
  __shared__ __attribute__((aligned(16))) ushort POOL[2][128 * 64 + 2 * 64 * 64];
  __shared__ float LM[4][64];
  float* OM = (float*)POOL;             // epilogue alias: 16 x 1024 f32 = 64 KB

  // XCD-chunked swizzle: 256 blocks = 8 XCDs x 32; XCD x gets orig in
  // [x*32, x*32+32) = 4 whole bh (8 qt each). Bijective.
  const int L = blockIdx.x + (blockIdx.y << 3);
  const int orig = (L & 7) * 32 + (L >> 3);
  const int qt = orig & 7, bh = orig >> 3;
  const int b = bh >> 4, h = bh & 15;
  const int tid = threadIdx.x, wid = tid >> 6, lane = tid & 63;
  const int l31 = lane & 31, hi = lane >> 5, l7 = lane & 7;
  const int j3 = l31 >> 3;                  // row bits 3-4 of per-lane rows
  const int qgi = wid >> 1, kh = wid & 1;   // q-group 0..3, key-half 0..1

  // Q B-frags: 64 q rows (2 subtiles of 32). col=q=l31, k=s*16+8*hi+r.
  const ushort* qb = qg + ((size_t)bh * S_ + qt * 256 + qgi * 64) * DK_;
  s8vec bq[2][4];
#pragma unroll
  for (int qs = 0; qs < 2; ++qs)
#pragma unroll
    for (int s = 0; s < 4; ++s)
      bq[qs][s] = *(const s8vec*)(qb + (size_t)(qs * 32 + l31) * DK_ + s * 16 + hi * 8);

  f16vec o[2][2];           // O^T accum: [dv-half][q-subtile]
  float lsum[2] = {0.f, 0.f};
#pragma unroll
  for (int dvh = 0; dvh < 2; ++dvh)
#pragma unroll
    for (int qs = 0; qs < 2; ++qs)
#pragma unroll
      for (int i = 0; i < 16; ++i) o[dvh][qs][i] = 0.f;

  // staging: thread t -> K rows {srow, srow+64}, V dv-row srow x key-halves.
  // LDS[row][g] = global[row][g ^ (row&7) ^ ((row>>3)&7)]; dest linear.
  // srow = wid*8 + (lane>>3): srow&7 = lane>>3, (srow>>3)&7 = wid (also +64).
  const int srow = wid * 8 + (lane >> 3);       // 0..63
  const int gk = (lane & 7) ^ (lane >> 3) ^ wid;
  const ushort* kb_ = kg + (size_t)bh * S_ * DK_;
  const ushort* vb_ = vtg + (size_t)bh * 64 * S_ + (size_t)srow * S_;

#define STAGE(buf, kt_)                                                     \
  do {                                                                      \
    const ushort* kk0 = kb_ + (size_t)((kt_) * 128 + srow) * DK_ + gk * 8;  \
    gl_lds16(kk0, &POOL[buf][wid * 512]);                                   \
    gl_lds16(kk0 + (size_t)64 * DK_, &POOL[buf][4096 + wid * 512]);         \
    gl_lds16(vb_ + (kt_) * 128 + gk * 8, &POOL[buf][8192 + wid * 512]);     \
    gl_lds16(vb_ + (kt_) * 128 + 64 + gk * 8,                               \
             &POOL[buf][8192 + 4096 + wid * 512]);                          \
  } while (0)

  STAGE(0, 0);
  __syncthreads();                      // drain prologue stage

  for (int kt = 0; kt < S_ / 128; ++kt) {
    const int cur = kt & 1;
    if (kt + 1 < S_ / 128) STAGE(cur ^ 1, kt + 1);   // flies under compute

    const ushort* ksb = POOL[cur];
    const ushort* vtb = POOL[cur] + 8192;
#pragma unroll
    for (int c = 0; c < 2; ++c) {
      const int row0 = kh * 64 + c * 32 + l31;       // (row0>>3)&7 = (c*4+j3)&7
      const int akx = l7 ^ ((c * 4 + j3) & 7);
      s8vec ak[4];
#pragma unroll
      for (int s = 0; s < 4; ++s)
        ak[s] = *(const s8vec*)&ksb[row0 * 64 + ((2 * s + hi) ^ akx) * 8];

      f16vec st[2];
#pragma unroll
      for (int qs = 0; qs < 2; ++qs)
#pragma unroll
        for (int i = 0; i < 16; ++i) st[qs][i] = 0.f;
      __builtin_amdgcn_s_setprio(1);
#pragma unroll
      for (int s = 0; s < 4; ++s) {
        st[0] = mfma32(ak[s], bq[0][s], st[0]);
        st[1] = mfma32(ak[s], bq[1][s], st[1]);
      }
      __builtin_amdgcn_s_setprio(0);

#pragma unroll
      for (int qs = 0; qs < 2; ++qs) {
        float p[16];
#pragma unroll
        for (int r = 0; r < 16; ++r) p[r] = exp2f_fast(st[qs][r]);
        lsum[qs] +=
            (((p[0] + p[1]) + (p[2] + p[3])) + ((p[4] + p[5]) + (p[6] + p[7]))) +
            (((p[8] + p[9]) + (p[10] + p[11])) + ((p[12] + p[13]) + (p[14] + p[15])));
        // per 16-key window m: build PV B-frag (k = 8*hi + 0..7, col = q)
#pragma unroll
        for (int m = 0; m < 2; ++m) {
          unsigned u01 = pk2(p[m * 8 + 0], p[m * 8 + 1]);
          unsigned u23 = pk2(p[m * 8 + 2], p[m * 8 + 3]);
          unsigned u89 = pk2(p[m * 8 + 4], p[m * 8 + 5]);
          unsigned uAB = pk2(p[m * 8 + 6], p[m * 8 + 7]);
          asm("v_permlane32_swap_b32 %0, %1" : "+v"(u01), "+v"(u89));
          asm("v_permlane32_swap_b32 %0, %1" : "+v"(u23), "+v"(uAB));
          union { unsigned u[4]; s8vec v; } pb;
          pb.u[0] = u01; pb.u[1] = u23; pb.u[2] = u89; pb.u[3] = uAB;
          __builtin_amdgcn_s_setprio(1);
#pragma unroll
          for (int dvh = 0; dvh < 2; ++dvh) {
            // V LDS row = dvh*32 + l31: (row>>3)&7 = (dvh*4 + j3)&7
            s8vec av = *(const s8vec*)&vtb[kh * 4096 + (dvh * 32 + l31) * 64 +
                                           (((4 * c + 2 * m + hi) ^ l7 ^
                                             ((dvh * 4 + j3) & 7)) * 8)];
            o[dvh][qs] = mfma32(av, pb.v, o[dvh][qs]);
          }
          __builtin_amdgcn_s_setprio(0);
        }
      }
    }
    __syncthreads();                    // drains stage loads; all readers done
  }
#undef STAGE

  // reduce hi-halves (disjoint keys within this wave's half)
#pragma unroll
  for (int qs = 0; qs < 2; ++qs) lsum[qs] += __shfl_xor(lsum[qs], 32, 64);

  // merge kh pair in ONE round: kh=1 publishes into OM (64 KB alias over POOL);
  // kh=0 combines + normalizes + writes. Slot = qgi*4 + dvh*2 + qs (16 x 4 KB).
  if (kh == 1) {
#pragma unroll
    for (int dvh = 0; dvh < 2; ++dvh)
#pragma unroll
      for (int qs = 0; qs < 2; ++qs)
#pragma unroll
        for (int r = 0; r < 16; ++r)
          OM[(qgi * 4 + dvh * 2 + qs) * 1024 + r * 64 + lane] = o[dvh][qs][r];
    if (!hi) {
      LM[qgi][l31]      = lsum[0];
      LM[qgi][32 + l31] = lsum[1];
    }
  }
  __syncthreads();
  if (kh == 0) {
    float linv[2];
#pragma unroll
    for (int qs = 0; qs < 2; ++qs)
      linv[qs] = 1.0f / (lsum[qs] + LM[qgi][qs * 32 + l31]);
    float* ob = out + ((size_t)b * S_ + qt * 256 + qgi * 64) * D_ + h * DK_;
#pragma unroll
    for (int dvh = 0; dvh < 2; ++dvh)
#pragma unroll
      for (int qs = 0; qs < 2; ++qs)
#pragma unroll
        for (int qd = 0; qd < 4; ++qd) {
          const int slot = (qgi * 4 + dvh * 2 + qs) * 1024;
          float4 vv;
          vv.x = (o[dvh][qs][qd * 4 + 0] + OM[slot + (qd * 4 + 0) * 64 + lane]) * linv[qs];
          vv.y = (o[dvh][qs][qd * 4 + 1] + OM[slot + (qd * 4 + 1) * 64 + lane]) * linv[qs];
          vv.z = (o[dvh][qs][qd * 4 + 2] + OM[slot + (qd * 4 + 2) * 64 + lane]) * linv[qs];
          vv.w = (o[dvh][qs][qd * 4 + 3] + OM[slot + (qd * 4 + 3) * 64 + lane]) * linv[qs];
          // dv = dvh*32 + qd*8 + 4*hi + {0..3}
          *(float4*)&ob[(size_t)(qs * 32 + l31) * D_ + dvh * 32 + qd * 8 + 4 * hi] = vv;
        }
  }
}

extern "C" void kernel_launch(void* const* d_in, const int* in_sizes, int n_in,
                              void* d_out, int out_size, void* d_ws, size_t ws_size,
                              hipStream_t stream) {
  const float* x  = (const float*)d_in[0];
  const float* Wq = (const float*)d_in[1];
  const float* Wk = (const float*)d_in[2];
  const float* Wv = (const float*)d_in[3];
  float* out = (float*)d_out;

  ushort* xb  = (ushort*)d_ws;                       // B*S*D bf16
  ushort* wbt = xb + (size_t)B_ * S_ * D_;           // [3072][1024] bf16
  ushort* qkv = wbt + (size_t)3 * D_ * D_;           // q,k: [b][h][s][64]; v: [b*1024+n1][s]
  const size_t per = (size_t)B_ * H_ * S_ * DK_;

  cvt_xw<<<4096 + 768, 256, 0, stream>>>(x, Wq, Wk, Wv, xb, wbt);
  proj_gemm<<<dim3(M_ / 256, N_ / 192), 512, 0, stream>>>(xb, wbt, qkv);
  attn<<<dim3(S_ / 256, B_ * H_), 512, 0, stream>>>(qkv, qkv + per, qkv + 2 * per, out);
}

// Round 13
// 160.612 us; speedup vs baseline: 1.0333x; 1.0333x over previous
//
#include <hip/hip_runtime.h>

#define B_ 2
#define S_ 2048
#define D_ 1024
#define H_ 16
#define DK_ 64
#define M_ (B_ * S_)   // 4096
#define N_ (3 * D_)    // 3072

typedef __bf16 bf16x8 __attribute__((ext_vector_type(8)));
typedef short s8vec __attribute__((ext_vector_type(8)));
typedef float f4vec __attribute__((ext_vector_type(4)));
typedef float f16vec __attribute__((ext_vector_type(16)));

static __device__ __forceinline__ ushort f2b(float f) {
  union { float f; unsigned u; } v; v.f = f;
  unsigned u = v.u;
  u += 0x7FFFu + ((u >> 16) & 1u);   // RNE to bf16
  return (ushort)(u >> 16);
}

static __device__ __forceinline__ unsigned pk2(float a, float b) {
#if __has_builtin(__builtin_amdgcn_cvt_pk_bf16_f32)
  typedef __bf16 b2 __attribute__((ext_vector_type(2)));
  b2 r = __builtin_amdgcn_cvt_pk_bf16_f32(a, b);
  return __builtin_bit_cast(unsigned, r);
#else
  return (unsigned)f2b(a) | ((unsigned)f2b(b) << 16);
#endif
}

static __device__ __forceinline__ float exp2f_fast(float x) {
#if __has_builtin(__builtin_amdgcn_exp2f)
  return __builtin_amdgcn_exp2f(x);
#else
  return __expf(x * 0.6931471805599453f);   // 2^x = e^(x ln2)
#endif
}

static __device__ __forceinline__ f4vec mfma16(s8vec a, s8vec b, f4vec c) {
  return __builtin_amdgcn_mfma_f32_16x16x32_bf16(
      __builtin_bit_cast(bf16x8, a), __builtin_bit_cast(bf16x8, b), c, 0, 0, 0);
}

static __device__ __forceinline__ f16vec mfma32(s8vec a, s8vec b, f16vec c) {
  return __builtin_amdgcn_mfma_f32_32x32x16_bf16(
      __builtin_bit_cast(bf16x8, a), __builtin_bit_cast(bf16x8, b), c, 0, 0, 0);
}

static __device__ __forceinline__ void gl_lds16(const ushort* g, ushort* l) {
  __builtin_amdgcn_global_load_lds(
      (const __attribute__((address_space(1))) unsigned*)g,
      (__attribute__((address_space(3))) unsigned*)l, 16, 0, 0);
}

// raw workgroup barrier: drains LDS (lgkmcnt) only — in-flight GLOBAL loads to
// VGPRs stay outstanding across the barrier (the whole point of reg-prefetch).
// 0xC07F = vmcnt(63) expcnt(7) lgkmcnt(0).
static __device__ __forceinline__ void wg_barrier_lds() {
  asm volatile("" ::: "memory");
  __builtin_amdgcn_s_waitcnt(0xC07F);
  __builtin_amdgcn_s_barrier();
  asm volatile("" ::: "memory");
}

// ---- fused input conversion: blocks [0,4096) convert x, [4096,4864) transpose W ----
// Wq (w==0) is pre-scaled by log2(e) so attn can use exp2 directly.
__global__ __launch_bounds__(256) void cvt_xw(const float* __restrict__ x,
                                              const float* __restrict__ Wq,
                                              const float* __restrict__ Wk,
                                              const float* __restrict__ Wv,
                                              ushort* __restrict__ xb,
                                              ushort* __restrict__ wbt) {
  __shared__ ushort T[64 * 72];
  const int t = threadIdx.x;
  if (blockIdx.x < 4096) {
    int i = blockIdx.x * 256 + t;
    float4 v = ((const float4*)x)[i];
    ushort4 o;
    o.x = f2b(v.x); o.y = f2b(v.y); o.z = f2b(v.z); o.w = f2b(v.w);
    ((ushort4*)xb)[i] = o;
    return;
  }
  const int r = blockIdx.x - 4096;                // 0..767
  const int w = r >> 8, h = (r >> 4) & 15, d0 = (r & 15) * 64;
  const float* W = (w == 0) ? Wq : (w == 1) ? Wk : Wv;
  const float sc = (w == 0) ? 1.4426950408889634f : 1.0f;
  const float* src = W + (size_t)h * 65536 + (size_t)d0 * 64;   // [64 d][64 k]
#pragma unroll
  for (int j = 0; j < 4; ++j) {
    int idx = j * 256 + t;
    int dr = idx >> 4, kc = (idx & 15) * 4;
    float4 v = *(const float4*)(src + dr * 64 + kc);
    T[(kc + 0) * 72 + dr] = f2b(v.x * sc);
    T[(kc + 1) * 72 + dr] = f2b(v.y * sc);
    T[(kc + 2) * 72 + dr] = f2b(v.z * sc);
    T[(kc + 3) * 72 + dr] = f2b(v.w * sc);
  }
  __syncthreads();
  const int kk = t >> 2, dcg = (t & 3) * 16;
  ushort* dst = wbt + ((size_t)w * 1024 + h * 64 + kk) * 1024 + d0 + dcg;
  *(s8vec*)dst       = *(const s8vec*)&T[kk * 72 + dcg];
  *(s8vec*)(dst + 8) = *(const s8vec*)&T[kk * 72 + dcg + 8];
}

// ---- fused QKV projection (round-10 version, PASSED twice): 256x192 tile,
// BK=64, 512 thr, 2-phase dbuf LDS, extended bank swizzle, __syncthreads
// schedule, 1 block/CU ----
__global__ __launch_bounds__(512) void proj_gemm(const ushort* __restrict__ xb,
                                                 const ushort* __restrict__ wbt,
                                                 ushort* __restrict__ qkv) {
  __shared__ __attribute__((aligned(16))) ushort As[2][256 * 64];
  __shared__ __attribute__((aligned(16))) ushort Bs[2][192 * 64];
  const int tid = threadIdx.x, wid = tid >> 6, lane = tid & 63;
  const int quad = lane >> 4, l15 = lane & 15;
  const int wm = wid & 1, wn = wid >> 1;
  const int m0 = blockIdx.x * 256, n0 = blockIdx.y * 192;

  f4vec acc[8][3];
#pragma unroll
  for (int mb = 0; mb < 8; mb++)
#pragma unroll
    for (int nb = 0; nb < 3; nb++)
#pragma unroll
      for (int i = 0; i < 4; i++) acc[mb][nb][i] = 0.f;

  const int sr = tid >> 3, sg = tid & 7;
  const int gk = sg ^ (sr & 7) ^ ((sr >> 3) & 7);
  const ushort* Ab = xb + (size_t)m0 * D_;
  const ushort* Bb = wbt + (size_t)n0 * D_;

#define PSTAGE(buf, k0_)                                                    \
  do {                                                                      \
    _Pragma("unroll")                                                       \
    for (int j = 0; j < 4; ++j)                                             \
      gl_lds16(Ab + (size_t)(j * 64 + sr) * D_ + (k0_) + gk * 8,            \
               &As[buf][(j * 64 + wid * 8) * 64]);                          \
    _Pragma("unroll")                                                       \
    for (int j = 0; j < 3; ++j)                                             \
      gl_lds16(Bb + (size_t)(j * 64 + sr) * D_ + (k0_) + gk * 8,            \
               &Bs[buf][(j * 64 + wid * 8) * 64]);                          \
  } while (0)

#define PCOMP(buf)                                                          \
  do {                                                                      \
    _Pragma("unroll")                                                       \
    for (int kb = 0; kb < 2; ++kb) {                                        \
      s8vec af[8], bf[3];                                                   \
      _Pragma("unroll")                                                     \
      for (int mb = 0; mb < 8; ++mb) {                                      \
        int m = wm * 128 + mb * 16 + l15;                                   \
        int gpos = (kb * 4 + quad) ^ (m & 7) ^ ((mb * 2 + (l15 >> 3)) & 7); \
        af[mb] = *(const s8vec*)&As[buf][m * 64 + gpos * 8];                \
      }                                                                     \
      _Pragma("unroll")                                                     \
      for (int nb = 0; nb < 3; ++nb) {                                      \
        int n = wn * 48 + nb * 16 + l15;                                    \
        int gpos = (kb * 4 + quad) ^ (n & 7) ^                              \
                   ((wn * 6 + nb * 2 + (l15 >> 3)) & 7);                    \
        bf[nb] = *(const s8vec*)&Bs[buf][n * 64 + gpos * 8];                \
      }                                                                     \
      _Pragma("unroll")                                                     \
      for (int mb = 0; mb < 8; ++mb)                                        \
        _Pragma("unroll")                                                   \
        for (int nb = 0; nb < 3; ++nb)                                      \
          acc[mb][nb] = mfma16(af[mb], bf[nb], acc[mb][nb]);                \
    }                                                                       \
  } while (0)

  PSTAGE(0, 0);
  __syncthreads();
  for (int t = 0; t < 15; ++t) {
    const int cur = t & 1;
    PSTAGE(cur ^ 1, (t + 1) * 64);
    PCOMP(cur);
    __syncthreads();
  }
  PCOMP(1);
#undef PSTAGE
#undef PCOMP

  const size_t per = (size_t)B_ * H_ * S_ * DK_;
  ushort* vt = qkv + 2 * per;
#pragma unroll
  for (int mb = 0; mb < 8; ++mb)
#pragma unroll
    for (int nb = 0; nb < 3; ++nb) {
      const int n1g = n0 + wn * 48 + nb * 16 + l15;
      const int w = n1g >> 10, n1 = n1g & 1023;
      if (w == 2) {
#pragma unroll
        for (int i = 0; i < 4; ++i) {
          int m = m0 + wm * 128 + mb * 16 + quad * 4 + i;
          int b = m >> 11, s = m & 2047;
          vt[((size_t)b * 1024 + n1) * S_ + s] = f2b(acc[mb][nb][i]);
        }
      } else {
#pragma unroll
        for (int i = 0; i < 4; ++i) {
          int m = m0 + wm * 128 + mb * 16 + quad * 4 + i;
          int b = m >> 11, s = m & 2047;
          qkv[(size_t)w * per + (((size_t)b * H_ + (n1 >> 6)) * S_ + s) * 64 + (n1 & 63)] =
              f2b(acc[mb][nb][i]);
        }
      }
    }
}

// ---- flash attention v15 = round-6 v9 VERBATIM (passed, 53.9 us: fat waves
// Q-tile 256, 32x32 MFMA, reg-prefetch staging, lgkm-only barriers, simple
// l7 swizzle, 2-round epilogue merge) + ONLY the XCD-chunked grid remap
// (verified in passing v12 at this exact geometry: FETCH 70->12.4 MB).
// The extended LDS swizzle with reg-prefetch staging failed twice (rounds
// 11/12, identical absmax) — dropped; accept ~2.1M conflict cycles (~1.6%).
__global__ __launch_bounds__(512) void attn(const ushort* __restrict__ qg,
                                            const ushort* __restrict__ kg,
                                            const ushort* __restrict__ vtg,
                                            float* __restrict__ out) {
  // pooled LDS: Ks 128x64 (16KB) + Vt 2x64x64 (16KB); epilogue aliases the
  // same 32KB as OM (2 q-groups per round x 4096 floats).
  __shared__ __attribute__((aligned(16))) ushort KV[128 * 64 + 2 * 64 * 64];
  __shared__ float LM[4][64];
  ushort* Ks  = KV;
  ushort* Vt0 = KV + 128 * 64;          // Vt[hf] = Vt0 + hf*4096
  float*  OM  = (float*)KV;

  // XCD-chunked remap (verified in v12): 256 blocks = 8 XCDs x 32; XCD x gets
  // contiguous orig range [x*32, x*32+32) = 4 whole bh. Bijective.
  const int L = blockIdx.x + (blockIdx.y << 3);
  const int orig = (L & 7) * 32 + (L >> 3);
  const int qt = orig & 7, bh = orig >> 3;
  const int b = bh >> 4, h = bh & 15;
  const int tid = threadIdx.x, wid = tid >> 6, lane = tid & 63;
  const int l31 = lane & 31, hi = lane >> 5, l7 = lane & 7;
  const int qgi = wid >> 1, kh = wid & 1;   // q-group 0..3, key-half 0..1

  // Q B-frags: 64 q rows (2 subtiles of 32), 4 d-slices of 16.
  // B layout: col=q=l31, k = s*16 + 8*hi + r.
  const ushort* qb = qg + ((size_t)bh * S_ + qt * 256 + qgi * 64) * DK_;
  s8vec bq[2][4];
#pragma unroll
  for (int qs = 0; qs < 2; ++qs)
#pragma unroll
    for (int s = 0; s < 4; ++s)
      bq[qs][s] = *(const s8vec*)(qb + (size_t)(qs * 32 + l31) * DK_ + s * 16 + hi * 8);

  f16vec o[2][2];           // O^T accum: [dv-half][q-subtile], 32x32 C each
  float lsum[2] = {0.f, 0.f};
#pragma unroll
  for (int dvh = 0; dvh < 2; ++dvh)
#pragma unroll
    for (int qs = 0; qs < 2; ++qs)
#pragma unroll
      for (int i = 0; i < 16; ++i) o[dvh][qs][i] = 0.f;

  // staging: 512 threads stage K 128x64 + V 64x128 per tile (4 loads/thread).
  // LDS[row][gs] = global[row][gs ^ (row&7)]  ((r+64)&7 == r&7).
  const int r6 = tid >> 3, gs = tid & 7;        // r6 0..63, group 0..7
  const int gk = gs ^ (r6 & 7);
  const ushort* kb_ = kg + (size_t)bh * S_ * DK_;
  const ushort* vb_ = vtg + (size_t)bh * 64 * S_ + (size_t)r6 * S_;

  s8vec kr[2], vr[2];
  kr[0] = *(const s8vec*)(kb_ + (size_t)r6 * DK_ + gk * 8);
  kr[1] = *(const s8vec*)(kb_ + (size_t)(64 + r6) * DK_ + gk * 8);
  vr[0] = *(const s8vec*)(vb_ + gk * 8);
  vr[1] = *(const s8vec*)(vb_ + 64 + gk * 8);

  for (int kt = 0; kt < S_ / 128; ++kt) {
    wg_barrier_lds();                       // readers of previous tile done
    *(s8vec*)&Ks[r6 * 64 + gs * 8]        = kr[0];
    *(s8vec*)&Ks[(64 + r6) * 64 + gs * 8] = kr[1];
    *(s8vec*)&Vt0[r6 * 64 + gs * 8]       = vr[0];
    *(s8vec*)&Vt0[4096 + r6 * 64 + gs * 8] = vr[1];
    if (kt + 1 < S_ / 128) {                // prefetch next tile
      const ushort* kn = kb_ + (size_t)(kt + 1) * 128 * DK_;
      kr[0] = *(const s8vec*)(kn + (size_t)r6 * DK_ + gk * 8);
      kr[1] = *(const s8vec*)(kn + (size_t)(64 + r6) * DK_ + gk * 8);
      const ushort* vn = vb_ + (kt + 1) * 128;
      vr[0] = *(const s8vec*)(vn + gk * 8);
      vr[1] = *(const s8vec*)(vn + 64 + gk * 8);
    }
    wg_barrier_lds();                       // staging writes visible

    // this wave: keys [kh*64, kh*64+64) as 2 chunks of 32, for 64 q
#pragma unroll
    for (int c = 0; c < 2; ++c) {
      const int row0 = kh * 64 + c * 32 + l31;    // key row; row0&7 == l7
      s8vec ak[4];
#pragma unroll
      for (int s = 0; s < 4; ++s)
        ak[s] = *(const s8vec*)&Ks[row0 * 64 + (((2 * s + hi)) ^ l7) * 8];

      f16vec st[2];
#pragma unroll
      for (int qs = 0; qs < 2; ++qs)
#pragma unroll
        for (int i = 0; i < 16; ++i) st[qs][i] = 0.f;
#pragma unroll
      for (int s = 0; s < 4; ++s) {
        st[0] = mfma32(ak[s], bq[0][s], st[0]);
        st[1] = mfma32(ak[s], bq[1][s], st[1]);
      }

#pragma unroll
      for (int qs = 0; qs < 2; ++qs) {
        float p[16];
#pragma unroll
        for (int r = 0; r < 16; ++r) p[r] = exp2f_fast(st[qs][r]);
        float s0 = ((p[0] + p[1]) + (p[2] + p[3])) + ((p[4] + p[5]) + (p[6] + p[7]));
        float s1 = ((p[8] + p[9]) + (p[10] + p[11])) + ((p[12] + p[13]) + (p[14] + p[15]));
        lsum[qs] += s0 + s1;
        // per 16-key window m: build PV B-frag (k = 8*hi + 0..7, col = q)
#pragma unroll
        for (int m = 0; m < 2; ++m) {
          unsigned u01 = pk2(p[m * 8 + 0], p[m * 8 + 1]);   // keys {0,1}+4hi
          unsigned u23 = pk2(p[m * 8 + 2], p[m * 8 + 3]);   // keys {2,3}+4hi
          unsigned u89 = pk2(p[m * 8 + 4], p[m * 8 + 5]);   // keys {8,9}+4hi
          unsigned uAB = pk2(p[m * 8 + 6], p[m * 8 + 7]);   // keys {10,11}+4hi
          // swap32: a'=[a.lo|b.lo], b'=[a.hi|b.hi]
          asm("v_permlane32_swap_b32 %0, %1" : "+v"(u01), "+v"(u89));
          asm("v_permlane32_swap_b32 %0, %1" : "+v"(u23), "+v"(uAB));
          union { unsigned u[4]; s8vec v; } pb;
          pb.u[0] = u01;   // w0: [{0,1}|{8,9}]
          pb.u[1] = u23;   // w1: [{2,3}|{10,11}]
          pb.u[2] = u89;   // w2: [{4,5}|{12,13}]
          pb.u[3] = uAB;   // w3: [{6,7}|{14,15}]
#pragma unroll
          for (int dvh = 0; dvh < 2; ++dvh) {
            s8vec av = *(const s8vec*)&Vt0[kh * 4096 + (dvh * 32 + l31) * 64 +
                                           ((4 * c + 2 * m + hi) ^ l7) * 8];
            o[dvh][qs] = mfma32(av, pb.v, o[dvh][qs]);
          }
        }
      }
    }
  }

  // per-q partial sum over this wave's key-half (hi-halves hold disjoint keys)
#pragma unroll
  for (int qs = 0; qs < 2; ++qs) lsum[qs] += __shfl_xor(lsum[qs], 32, 64);

  // merge key-halves: kh=1 waves publish via LDS (aliased over Ks/Vt),
  // kh=0 waves combine + normalize + write. 2 rounds of 2 q-groups (32 KB).
  __syncthreads();
#pragma unroll
  for (int rnd = 0; rnd < 2; ++rnd) {
    if (kh == 1 && (qgi >> 1) == rnd) {
      const int slot = (qgi & 1) * 4;
#pragma unroll
      for (int dvh = 0; dvh < 2; ++dvh)
#pragma unroll
        for (int qs = 0; qs < 2; ++qs)
#pragma unroll
          for (int r = 0; r < 16; ++r)
            OM[(slot + dvh * 2 + qs) * 1024 + r * 64 + lane] = o[dvh][qs][r];
      if (!hi) {
        LM[qgi][l31]      = lsum[0];
        LM[qgi][32 + l31] = lsum[1];
      }
    }
    __syncthreads();
    if (kh == 0 && (qgi >> 1) == rnd) {
      const int slot = (qgi & 1) * 4;
      float linv[2];
#pragma unroll
      for (int qs = 0; qs < 2; ++qs)
        linv[qs] = 1.0f / (lsum[qs] + LM[qgi][qs * 32 + l31]);
      float* ob = out + ((size_t)b * S_ + qt * 256 + qgi * 64) * D_ + h * DK_;
#pragma unroll
      for (int dvh = 0; dvh < 2; ++dvh)
#pragma unroll
        for (int qs = 0; qs < 2; ++qs)
#pragma unroll
          for (int qd = 0; qd < 4; ++qd) {
            float4 vv;
            vv.x = (o[dvh][qs][qd * 4 + 0] +
                    OM[(slot + dvh * 2 + qs) * 1024 + (qd * 4 + 0) * 64 + lane]) * linv[qs];
            vv.y = (o[dvh][qs][qd * 4 + 1] +
                    OM[(slot + dvh * 2 + qs) * 1024 + (qd * 4 + 1) * 64 + lane]) * linv[qs];
            vv.z = (o[dvh][qs][qd * 4 + 2] +
                    OM[(slot + dvh * 2 + qs) * 1024 + (qd * 4 + 2) * 64 + lane]) * linv[qs];
            vv.w = (o[dvh][qs][qd * 4 + 3] +
                    OM[(slot + dvh * 2 + qs) * 1024 + (qd * 4 + 3) * 64 + lane]) * linv[qs];
            // dv = dvh*32 + qd*8 + 4*hi + {0..3}
            *(float4*)&ob[(size_t)(qs * 32 + l31) * D_ + dvh * 32 + qd * 8 + 4 * hi] = vv;
          }
    }
    __syncthreads();
  }
}

extern "C" void kernel_launch(void* const* d_in, const int* in_sizes, int n_in,
                              void* d_out, int out_size, void* d_ws, size_t ws_size,
                              hipStream_t stream) {
  const float* x  = (const float*)d_in[0];
  const float* Wq = (const float*)d_in[1];
  const float* Wk = (const float*)d_in[2];
  const float* Wv = (const float*)d_in[3];
  float* out = (float*)d_out;

  ushort* xb  = (ushort*)d_ws;                       // B*S*D bf16
  ushort* wbt = xb + (size_t)B_ * S_ * D_;           // [3072][1024] bf16
  ushort* qkv = wbt + (size_t)3 * D_ * D_;           // q,k: [b][h][s][64]; v: [b*1024+n1][s]
  const size_t per = (size_t)B_ * H_ * S_ * DK_;

  cvt_xw<<<4096 + 768, 256, 0, stream>>>(x, Wq, Wk, Wv, xb, wbt);
  proj_gemm<<<dim3(M_ / 256, N_ / 192), 512, 0, stream>>>(xb, wbt, qkv);
  attn<<<dim3(S_ / 256, B_ * H_), 512, 0, stream>>>(qkv, qkv + per, qkv + 2 * per, out);
}

// Round 15
// 157.654 us; speedup vs baseline: 1.0527x; 1.0188x over previous
//
#include <hip/hip_runtime.h>

#define B_ 2
#define S_ 2048
#define D_ 1024
#define H_ 16
#define DK_ 64
#define M_ (B_ * S_)   // 4096
#define N_ (3 * D_)    // 3072

typedef __bf16 bf16x8 __attribute__((ext_vector_type(8)));
typedef short s8vec __attribute__((ext_vector_type(8)));
typedef float f4vec __attribute__((ext_vector_type(4)));
typedef float f16vec __attribute__((ext_vector_type(16)));

static __device__ __forceinline__ ushort f2b(float f) {
  union { float f; unsigned u; } v; v.f = f;
  unsigned u = v.u;
  u += 0x7FFFu + ((u >> 16) & 1u);   // RNE to bf16
  return (ushort)(u >> 16);
}

static __device__ __forceinline__ unsigned pk2(float a, float b) {
#if __has_builtin(__builtin_amdgcn_cvt_pk_bf16_f32)
  typedef __bf16 b2 __attribute__((ext_vector_type(2)));
  b2 r = __builtin_amdgcn_cvt_pk_bf16_f32(a, b);
  return __builtin_bit_cast(unsigned, r);
#else
  return (unsigned)f2b(a) | ((unsigned)f2b(b) << 16);
#endif
}

static __device__ __forceinline__ float exp2f_fast(float x) {
#if __has_builtin(__builtin_amdgcn_exp2f)
  return __builtin_amdgcn_exp2f(x);
#else
  return __expf(x * 0.6931471805599453f);   // 2^x = e^(x ln2)
#endif
}

static __device__ __forceinline__ f4vec mfma16(s8vec a, s8vec b, f4vec c) {
  return __builtin_amdgcn_mfma_f32_16x16x32_bf16(
      __builtin_bit_cast(bf16x8, a), __builtin_bit_cast(bf16x8, b), c, 0, 0, 0);
}

static __device__ __forceinline__ f16vec mfma32(s8vec a, s8vec b, f16vec c) {
  return __builtin_amdgcn_mfma_f32_32x32x16_bf16(
      __builtin_bit_cast(bf16x8, a), __builtin_bit_cast(bf16x8, b), c, 0, 0, 0);
}

static __device__ __forceinline__ void gl_lds16(const ushort* g, ushort* l) {
  __builtin_amdgcn_global_load_lds(
      (const __attribute__((address_space(1))) unsigned*)g,
      (__attribute__((address_space(3))) unsigned*)l, 16, 0, 0);
}

// raw workgroup barrier: drains LDS (lgkmcnt) only — in-flight GLOBAL loads to
// VGPRs stay outstanding across the barrier (the whole point of reg-prefetch).
// 0xC07F = vmcnt(63) expcnt(7) lgkmcnt(0).
static __device__ __forceinline__ void wg_barrier_lds() {
  asm volatile("" ::: "memory");
  __builtin_amdgcn_s_waitcnt(0xC07F);
  __builtin_amdgcn_s_barrier();
  asm volatile("" ::: "memory");
}

// ---- fused input conversion: blocks [0,4096) convert x, [4096,4864) transpose W ----
// Wq (w==0) is pre-scaled by log2(e) so attn can use exp2 directly.
__global__ __launch_bounds__(256) void cvt_xw(const float* __restrict__ x,
                                              const float* __restrict__ Wq,
                                              const float* __restrict__ Wk,
                                              const float* __restrict__ Wv,
                                              ushort* __restrict__ xb,
                                              ushort* __restrict__ wbt) {
  __shared__ ushort T[64 * 72];
  const int t = threadIdx.x;
  if (blockIdx.x < 4096) {
    int i = blockIdx.x * 256 + t;
    float4 v = ((const float4*)x)[i];
    ushort4 o;
    o.x = f2b(v.x); o.y = f2b(v.y); o.z = f2b(v.z); o.w = f2b(v.w);
    ((ushort4*)xb)[i] = o;
    return;
  }
  const int r = blockIdx.x - 4096;                // 0..767
  const int w = r >> 8, h = (r >> 4) & 15, d0 = (r & 15) * 64;
  const float* W = (w == 0) ? Wq : (w == 1) ? Wk : Wv;
  const float sc = (w == 0) ? 1.4426950408889634f : 1.0f;
  const float* src = W + (size_t)h * 65536 + (size_t)d0 * 64;   // [64 d][64 k]
#pragma unroll
  for (int j = 0; j < 4; ++j) {
    int idx = j * 256 + t;
    int dr = idx >> 4, kc = (idx & 15) * 4;
    float4 v = *(const float4*)(src + dr * 64 + kc);
    T[(kc + 0) * 72 + dr] = f2b(v.x * sc);
    T[(kc + 1) * 72 + dr] = f2b(v.y * sc);
    T[(kc + 2) * 72 + dr] = f2b(v.z * sc);
    T[(kc + 3) * 72 + dr] = f2b(v.w * sc);
  }
  __syncthreads();
  const int kk = t >> 2, dcg = (t & 3) * 16;
  ushort* dst = wbt + ((size_t)w * 1024 + h * 64 + kk) * 1024 + d0 + dcg;
  *(s8vec*)dst       = *(const s8vec*)&T[kk * 72 + dcg];
  *(s8vec*)(dst + 8) = *(const s8vec*)&T[kk * 72 + dcg + 8];
}

// ---- fused QKV projection v16: round-10 proven structure (256x192 tile,
// BK=64, 512 thr, 2-phase dbuf, extended bank swizzle) + COUNTED-vmcnt (T4):
// per step {PSTAGE(next); s_waitcnt vmcnt(7); s_barrier; PCOMP(cur); s_barrier}.
// vmcnt(7) waits only the PREVIOUS step's 7 loads (ordered retirement); the 7
// just-issued loads fly across the barrier and the whole compute phase —
// removes __syncthreads' implicit vmcnt(0) drain of just-issued loads (at
// 1 block/CU there is no other block to hide that stall).
// Encodings cross-checked vs working 0xC07F (gfx9 layout: vmcnt[3:0]=b3:0,
// expcnt=b6:4, lgkmcnt=b11:8, vmcnt[5:4]=b15:14):
//   0x0F77 = vmcnt(7) expcnt(7) lgkmcnt(15)   [no exp/lgkm wait]
//   0x0F70 = vmcnt(0) expcnt(7) lgkmcnt(15)
// Round-12 run (this proj reverted, failure persisted) exonerated this
// schedule of the round-11 correctness failure. No divergent barriers, no
// cross-wave wait cycles — deadlock not constructible; round-14 container
// failure was environmental (same signature as round 7, which passed on
// resubmit).
__global__ __launch_bounds__(512) void proj_gemm(const ushort* __restrict__ xb,
                                                 const ushort* __restrict__ wbt,
                                                 ushort* __restrict__ qkv) {
  __shared__ __attribute__((aligned(16))) ushort As[2][256 * 64];
  __shared__ __attribute__((aligned(16))) ushort Bs[2][192 * 64];
  const int tid = threadIdx.x, wid = tid >> 6, lane = tid & 63;
  const int quad = lane >> 4, l15 = lane & 15;
  const int wm = wid & 1, wn = wid >> 1;
  const int m0 = blockIdx.x * 256, n0 = blockIdx.y * 192;

  f4vec acc[8][3];
#pragma unroll
  for (int mb = 0; mb < 8; mb++)
#pragma unroll
    for (int nb = 0; nb < 3; nb++)
#pragma unroll
      for (int i = 0; i < 4; i++) acc[mb][nb][i] = 0.f;

  const int sr = tid >> 3, sg = tid & 7;
  const int gk = sg ^ (sr & 7) ^ ((sr >> 3) & 7);
  const ushort* Ab = xb + (size_t)m0 * D_;
  const ushort* Bb = wbt + (size_t)n0 * D_;

#define PSTAGE(buf, k0_)                                                    \
  do {                                                                      \
    _Pragma("unroll")                                                       \
    for (int j = 0; j < 4; ++j)                                             \
      gl_lds16(Ab + (size_t)(j * 64 + sr) * D_ + (k0_) + gk * 8,            \
               &As[buf][(j * 64 + wid * 8) * 64]);                          \
    _Pragma("unroll")                                                       \
    for (int j = 0; j < 3; ++j)                                             \
      gl_lds16(Bb + (size_t)(j * 64 + sr) * D_ + (k0_) + gk * 8,            \
               &Bs[buf][(j * 64 + wid * 8) * 64]);                          \
  } while (0)

#define PCOMP(buf)                                                          \
  do {                                                                      \
    _Pragma("unroll")                                                       \
    for (int kb = 0; kb < 2; ++kb) {                                        \
      s8vec af[8], bf[3];                                                   \
      _Pragma("unroll")                                                     \
      for (int mb = 0; mb < 8; ++mb) {                                      \
        int m = wm * 128 + mb * 16 + l15;                                   \
        int gpos = (kb * 4 + quad) ^ (m & 7) ^ ((mb * 2 + (l15 >> 3)) & 7); \
        af[mb] = *(const s8vec*)&As[buf][m * 64 + gpos * 8];                \
      }                                                                     \
      _Pragma("unroll")                                                     \
      for (int nb = 0; nb < 3; ++nb) {                                      \
        int n = wn * 48 + nb * 16 + l15;                                    \
        int gpos = (kb * 4 + quad) ^ (n & 7) ^                              \
                   ((wn * 6 + nb * 2 + (l15 >> 3)) & 7);                    \
        bf[nb] = *(const s8vec*)&Bs[buf][n * 64 + gpos * 8];                \
      }                                                                     \
      _Pragma("unroll")                                                     \
      for (int mb = 0; mb < 8; ++mb)                                        \
        _Pragma("unroll")                                                   \
        for (int nb = 0; nb < 3; ++nb)                                      \
          acc[mb][nb] = mfma16(af[mb], bf[nb], acc[mb][nb]);                \
    }                                                                       \
  } while (0)

  PSTAGE(0, 0);
  for (int t = 0; t < 15; ++t) {
    const int cur = t & 1;
    PSTAGE(cur ^ 1, (t + 1) * 64);      // 7 new loads join 7 old in flight
    asm volatile("" ::: "memory");
    __builtin_amdgcn_s_waitcnt(0x0F77); // vmcnt(7): oldest 7 (cur buf) landed
    __builtin_amdgcn_s_barrier();       // all waves' cur-buf loads landed
    asm volatile("" ::: "memory");
    PCOMP(cur);
    asm volatile("" ::: "memory");
    __builtin_amdgcn_s_barrier();       // all reads of cur done before re-stage
    asm volatile("" ::: "memory");
  }
  asm volatile("" ::: "memory");
  __builtin_amdgcn_s_waitcnt(0x0F70);   // vmcnt(0): last tile's loads landed
  __builtin_amdgcn_s_barrier();
  asm volatile("" ::: "memory");
  PCOMP(1);                             // tile 15 (staged in buf 1)
#undef PSTAGE
#undef PCOMP

  const size_t per = (size_t)B_ * H_ * S_ * DK_;
  ushort* vt = qkv + 2 * per;
#pragma unroll
  for (int mb = 0; mb < 8; ++mb)
#pragma unroll
    for (int nb = 0; nb < 3; ++nb) {
      const int n1g = n0 + wn * 48 + nb * 16 + l15;
      const int w = n1g >> 10, n1 = n1g & 1023;
      if (w == 2) {
#pragma unroll
        for (int i = 0; i < 4; ++i) {
          int m = m0 + wm * 128 + mb * 16 + quad * 4 + i;
          int b = m >> 11, s = m & 2047;
          vt[((size_t)b * 1024 + n1) * S_ + s] = f2b(acc[mb][nb][i]);
        }
      } else {
#pragma unroll
        for (int i = 0; i < 4; ++i) {
          int m = m0 + wm * 128 + mb * 16 + quad * 4 + i;
          int b = m >> 11, s = m & 2047;
          qkv[(size_t)w * per + (((size_t)b * H_ + (n1 >> 6)) * S_ + s) * 64 + (n1 & 63)] =
              f2b(acc[mb][nb][i]);
        }
      }
    }
}

// ---- flash attention (round-13 version, PASSED at 55.1 us): v9 fat-wave
// structure (Q-tile 256, 32x32 MFMA, reg-prefetch staging, lgkm-only barriers,
// simple l7 swizzle) + XCD-chunked grid remap (FETCH 12.4 MB verified).
__global__ __launch_bounds__(512) void attn(const ushort* __restrict__ qg,
                                            const ushort* __restrict__ kg,
                                            const ushort* __restrict__ vtg,
                                            float* __restrict__ out) {
  // pooled LDS: Ks 128x64 (16KB) + Vt 2x64x64 (16KB); epilogue aliases the
  // same 32KB as OM (2 q-groups per round x 4096 floats).
  __shared__ __attribute__((aligned(16))) ushort KV[128 * 64 + 2 * 64 * 64];
  __shared__ float LM[4][64];
  ushort* Ks  = KV;
  ushort* Vt0 = KV + 128 * 64;          // Vt[hf] = Vt0 + hf*4096
  float*  OM  = (float*)KV;

  // XCD-chunked remap: 256 blocks = 8 XCDs x 32; XCD x gets contiguous orig
  // range [x*32, x*32+32) = 4 whole bh. Bijective.
  const int L = blockIdx.x + (blockIdx.y << 3);
  const int orig = (L & 7) * 32 + (L >> 3);
  const int qt = orig & 7, bh = orig >> 3;
  const int b = bh >> 4, h = bh & 15;
  const int tid = threadIdx.x, wid = tid >> 6, lane = tid & 63;
  const int l31 = lane & 31, hi = lane >> 5, l7 = lane & 7;
  const int qgi = wid >> 1, kh = wid & 1;   // q-group 0..3, key-half 0..1

  // Q B-frags: 64 q rows (2 subtiles of 32), 4 d-slices of 16.
  // B layout: col=q=l31, k = s*16 + 8*hi + r.
  const ushort* qb = qg + ((size_t)bh * S_ + qt * 256 + qgi * 64) * DK_;
  s8vec bq[2][4];
#pragma unroll
  for (int qs = 0; qs < 2; ++qs)
#pragma unroll
    for (int s = 0; s < 4; ++s)
      bq[qs][s] = *(const s8vec*)(qb + (size_t)(qs * 32 + l31) * DK_ + s * 16 + hi * 8);

  f16vec o[2][2];           // O^T accum: [dv-half][q-subtile], 32x32 C each
  float lsum[2] = {0.f, 0.f};
#pragma unroll
  for (int dvh = 0; dvh < 2; ++dvh)
#pragma unroll
    for (int qs = 0; qs < 2; ++qs)
#pragma unroll
      for (int i = 0; i < 16; ++i) o[dvh][qs][i] = 0.f;

  // staging: 512 threads stage K 128x64 + V 64x128 per tile (4 loads/thread).
  // LDS[row][gs] = global[row][gs ^ (row&7)]  ((r+64)&7 == r&7).
  const int r6 = tid >> 3, gs = tid & 7;        // r6 0..63, group 0..7
  const int gk = gs ^ (r6 & 7);
  const ushort* kb_ = kg + (size_t)bh * S_ * DK_;
  const ushort* vb_ = vtg + (size_t)bh * 64 * S_ + (size_t)r6 * S_;

  s8vec kr[2], vr[2];
  kr[0] = *(const s8vec*)(kb_ + (size_t)r6 * DK_ + gk * 8);
  kr[1] = *(const s8vec*)(kb_ + (size_t)(64 + r6) * DK_ + gk * 8);
  vr[0] = *(const s8vec*)(vb_ + gk * 8);
  vr[1] = *(const s8vec*)(vb_ + 64 + gk * 8);

  for (int kt = 0; kt < S_ / 128; ++kt) {
    wg_barrier_lds();                       // readers of previous tile done
    *(s8vec*)&Ks[r6 * 64 + gs * 8]        = kr[0];
    *(s8vec*)&Ks[(64 + r6) * 64 + gs * 8] = kr[1];
    *(s8vec*)&Vt0[r6 * 64 + gs * 8]       = vr[0];
    *(s8vec*)&Vt0[4096 + r6 * 64 + gs * 8] = vr[1];
    if (kt + 1 < S_ / 128) {                // prefetch next tile
      const ushort* kn = kb_ + (size_t)(kt + 1) * 128 * DK_;
      kr[0] = *(const s8vec*)(kn + (size_t)r6 * DK_ + gk * 8);
      kr[1] = *(const s8vec*)(kn + (size_t)(64 + r6) * DK_ + gk * 8);
      const ushort* vn = vb_ + (kt + 1) * 128;
      vr[0] = *(const s8vec*)(vn + gk * 8);
      vr[1] = *(const s8vec*)(vn + 64 + gk * 8);
    }
    wg_barrier_lds();                       // staging writes visible

    // this wave: keys [kh*64, kh*64+64) as 2 chunks of 32, for 64 q
#pragma unroll
    for (int c = 0; c < 2; ++c) {
      const int row0 = kh * 64 + c * 32 + l31;    // key row; row0&7 == l7
      s8vec ak[4];
#pragma unroll
      for (int s = 0; s < 4; ++s)
        ak[s] = *(const s8vec*)&Ks[row0 * 64 + (((2 * s + hi)) ^ l7) * 8];

      f16vec st[2];
#pragma unroll
      for (int qs = 0; qs < 2; ++qs)
#pragma unroll
        for (int i = 0; i < 16; ++i) st[qs][i] = 0.f;
#pragma unroll
      for (int s = 0; s < 4; ++s) {
        st[0] = mfma32(ak[s], bq[0][s], st[0]);
        st[1] = mfma32(ak[s], bq[1][s], st[1]);
      }

#pragma unroll
      for (int qs = 0; qs < 2; ++qs) {
        float p[16];
#pragma unroll
        for (int r = 0; r < 16; ++r) p[r] = exp2f_fast(st[qs][r]);
        float s0 = ((p[0] + p[1]) + (p[2] + p[3])) + ((p[4] + p[5]) + (p[6] + p[7]));
        float s1 = ((p[8] + p[9]) + (p[10] + p[11])) + ((p[12] + p[13]) + (p[14] + p[15]));
        lsum[qs] += s0 + s1;
        // per 16-key window m: build PV B-frag (k = 8*hi + 0..7, col = q)
#pragma unroll
        for (int m = 0; m < 2; ++m) {
          unsigned u01 = pk2(p[m * 8 + 0], p[m * 8 + 1]);   // keys {0,1}+4hi
          unsigned u23 = pk2(p[m * 8 + 2], p[m * 8 + 3]);   // keys {2,3}+4hi
          unsigned u89 = pk2(p[m * 8 + 4], p[m * 8 + 5]);   // keys {8,9}+4hi
          unsigned uAB = pk2(p[m * 8 + 6], p[m * 8 + 7]);   // keys {10,11}+4hi
          // swap32: a'=[a.lo|b.lo], b'=[a.hi|b.hi]
          asm("v_permlane32_swap_b32 %0, %1" : "+v"(u01), "+v"(u89));
          asm("v_permlane32_swap_b32 %0, %1" : "+v"(u23), "+v"(uAB));
          union { unsigned u[4]; s8vec v; } pb;
          pb.u[0] = u01;   // w0: [{0,1}|{8,9}]
          pb.u[1] = u23;   // w1: [{2,3}|{10,11}]
          pb.u[2] = u89;   // w2: [{4,5}|{12,13}]
          pb.u[3] = uAB;   // w3: [{6,7}|{14,15}]
#pragma unroll
          for (int dvh = 0; dvh < 2; ++dvh) {
            s8vec av = *(const s8vec*)&Vt0[kh * 4096 + (dvh * 32 + l31) * 64 +
                                           ((4 * c + 2 * m + hi) ^ l7) * 8];
            o[dvh][qs] = mfma32(av, pb.v, o[dvh][qs]);
          }
        }
      }
    }
  }

  // per-q partial sum over this wave's key-half (hi-halves hold disjoint keys)
#pragma unroll
  for (int qs = 0; qs < 2; ++qs) lsum[qs] += __shfl_xor(lsum[qs], 32, 64);

  // merge key-halves: kh=1 waves publish via LDS (aliased over Ks/Vt),
  // kh=0 waves combine + normalize + write. 2 rounds of 2 q-groups (32 KB).
  __syncthreads();
#pragma unroll
  for (int rnd = 0; rnd < 2; ++rnd) {
    if (kh == 1 && (qgi >> 1) == rnd) {
      const int slot = (qgi & 1) * 4;
#pragma unroll
      for (int dvh = 0; dvh < 2; ++dvh)
#pragma unroll
        for (int qs = 0; qs < 2; ++qs)
#pragma unroll
          for (int r = 0; r < 16; ++r)
            OM[(slot + dvh * 2 + qs) * 1024 + r * 64 + lane] = o[dvh][qs][r];
      if (!hi) {
        LM[qgi][l31]      = lsum[0];
        LM[qgi][32 + l31] = lsum[1];
      }
    }
    __syncthreads();
    if (kh == 0 && (qgi >> 1) == rnd) {
      const int slot = (qgi & 1) * 4;
      float linv[2];
#pragma unroll
      for (int qs = 0; qs < 2; ++qs)
        linv[qs] = 1.0f / (lsum[qs] + LM[qgi][qs * 32 + l31]);
      float* ob = out + ((size_t)b * S_ + qt * 256 + qgi * 64) * D_ + h * DK_;
#pragma unroll
      for (int dvh = 0; dvh < 2; ++dvh)
#pragma unroll
        for (int qs = 0; qs < 2; ++qs)
#pragma unroll
          for (int qd = 0; qd < 4; ++qd) {
            float4 vv;
            vv.x = (o[dvh][qs][qd * 4 + 0] +
                    OM[(slot + dvh * 2 + qs) * 1024 + (qd * 4 + 0) * 64 + lane]) * linv[qs];
            vv.y = (o[dvh][qs][qd * 4 + 1] +
                    OM[(slot + dvh * 2 + qs) * 1024 + (qd * 4 + 1) * 64 + lane]) * linv[qs];
            vv.z = (o[dvh][qs][qd * 4 + 2] +
                    OM[(slot + dvh * 2 + qs) * 1024 + (qd * 4 + 2) * 64 + lane]) * linv[qs];
            vv.w = (o[dvh][qs][qd * 4 + 3] +
                    OM[(slot + dvh * 2 + qs) * 1024 + (qd * 4 + 3) * 64 + lane]) * linv[qs];
            // dv = dvh*32 + qd*8 + 4*hi + {0..3}
            *(float4*)&ob[(size_t)(qs * 32 + l31) * D_ + dvh * 32 + qd * 8 + 4 * hi] = vv;
          }
    }
    __syncthreads();
  }
}

extern "C" void kernel_launch(void* const* d_in, const int* in_sizes, int n_in,
                              void* d_out, int out_size, void* d_ws, size_t ws_size,
                              hipStream_t stream) {
  const float* x  = (const float*)d_in[0];
  const float* Wq = (const float*)d_in[1];
  const float* Wk = (const float*)d_in[2];
  const float* Wv = (const float*)d_in[3];
  float* out = (float*)d_out;

  ushort* xb  = (ushort*)d_ws;                       // B*S*D bf16
  ushort* wbt = xb + (size_t)B_ * S_ * D_;           // [3072][1024] bf16
  ushort* qkv = wbt + (size_t)3 * D_ * D_;           // q,k: [b][h][s][64]; v: [b*1024+n1][s]
  const size_t per = (size_t)B_ * H_ * S_ * DK_;

  cvt_xw<<<4096 + 768, 256, 0, stream>>>(x, Wq, Wk, Wv, xb, wbt);
  proj_gemm<<<dim3(M_ / 256, N_ / 192), 512, 0, stream>>>(xb, wbt, qkv);
  attn<<<dim3(S_ / 256, B_ * H_), 512, 0, stream>>>(qkv, qkv + per, qkv + 2 * per, out);
}

// Round 16
// 156.708 us; speedup vs baseline: 1.0591x; 1.0060x over previous
//
#include <hip/hip_runtime.h>

#define B_ 2
#define S_ 2048
#define D_ 1024
#define H_ 16
#define DK_ 64
#define M_ (B_ * S_)   // 4096
#define N_ (3 * D_)    // 3072

typedef __bf16 bf16x8 __attribute__((ext_vector_type(8)));
typedef short s8vec __attribute__((ext_vector_type(8)));
typedef float f4vec __attribute__((ext_vector_type(4)));
typedef float f16vec __attribute__((ext_vector_type(16)));

static __device__ __forceinline__ ushort f2b(float f) {
  union { float f; unsigned u; } v; v.f = f;
  unsigned u = v.u;
  u += 0x7FFFu + ((u >> 16) & 1u);   // RNE to bf16
  return (ushort)(u >> 16);
}

static __device__ __forceinline__ unsigned pk2(float a, float b) {
#if __has_builtin(__builtin_amdgcn_cvt_pk_bf16_f32)
  typedef __bf16 b2 __attribute__((ext_vector_type(2)));
  b2 r = __builtin_amdgcn_cvt_pk_bf16_f32(a, b);
  return __builtin_bit_cast(unsigned, r);
#else
  return (unsigned)f2b(a) | ((unsigned)f2b(b) << 16);
#endif
}

static __device__ __forceinline__ float exp2f_fast(float x) {
#if __has_builtin(__builtin_amdgcn_exp2f)
  return __builtin_amdgcn_exp2f(x);
#else
  return __expf(x * 0.6931471805599453f);   // 2^x = e^(x ln2)
#endif
}

static __device__ __forceinline__ f4vec mfma16(s8vec a, s8vec b, f4vec c) {
  return __builtin_amdgcn_mfma_f32_16x16x32_bf16(
      __builtin_bit_cast(bf16x8, a), __builtin_bit_cast(bf16x8, b), c, 0, 0, 0);
}

static __device__ __forceinline__ f16vec mfma32(s8vec a, s8vec b, f16vec c) {
  return __builtin_amdgcn_mfma_f32_32x32x16_bf16(
      __builtin_bit_cast(bf16x8, a), __builtin_bit_cast(bf16x8, b), c, 0, 0, 0);
}

static __device__ __forceinline__ void gl_lds16(const ushort* g, ushort* l) {
  __builtin_amdgcn_global_load_lds(
      (const __attribute__((address_space(1))) unsigned*)g,
      (__attribute__((address_space(3))) unsigned*)l, 16, 0, 0);
}

// raw workgroup barrier: drains LDS (lgkmcnt) only — in-flight GLOBAL loads to
// VGPRs stay outstanding across the barrier (the whole point of reg-prefetch).
// 0xC07F = vmcnt(63) expcnt(7) lgkmcnt(0).
static __device__ __forceinline__ void wg_barrier_lds() {
  asm volatile("" ::: "memory");
  __builtin_amdgcn_s_waitcnt(0xC07F);
  __builtin_amdgcn_s_barrier();
  asm volatile("" ::: "memory");
}

// ---- fused input conversion: blocks [0,4096) convert x, [4096,4864) transpose W ----
// Wq (w==0) is pre-scaled by log2(e) so attn can use exp2 directly.
__global__ __launch_bounds__(256) void cvt_xw(const float* __restrict__ x,
                                              const float* __restrict__ Wq,
                                              const float* __restrict__ Wk,
                                              const float* __restrict__ Wv,
                                              ushort* __restrict__ xb,
                                              ushort* __restrict__ wbt) {
  __shared__ ushort T[64 * 72];
  const int t = threadIdx.x;
  if (blockIdx.x < 4096) {
    int i = blockIdx.x * 256 + t;
    float4 v = ((const float4*)x)[i];
    ushort4 o;
    o.x = f2b(v.x); o.y = f2b(v.y); o.z = f2b(v.z); o.w = f2b(v.w);
    ((ushort4*)xb)[i] = o;
    return;
  }
  const int r = blockIdx.x - 4096;                // 0..767
  const int w = r >> 8, h = (r >> 4) & 15, d0 = (r & 15) * 64;
  const float* W = (w == 0) ? Wq : (w == 1) ? Wk : Wv;
  const float sc = (w == 0) ? 1.4426950408889634f : 1.0f;
  const float* src = W + (size_t)h * 65536 + (size_t)d0 * 64;   // [64 d][64 k]
#pragma unroll
  for (int j = 0; j < 4; ++j) {
    int idx = j * 256 + t;
    int dr = idx >> 4, kc = (idx & 15) * 4;
    float4 v = *(const float4*)(src + dr * 64 + kc);
    T[(kc + 0) * 72 + dr] = f2b(v.x * sc);
    T[(kc + 1) * 72 + dr] = f2b(v.y * sc);
    T[(kc + 2) * 72 + dr] = f2b(v.z * sc);
    T[(kc + 3) * 72 + dr] = f2b(v.w * sc);
  }
  __syncthreads();
  const int kk = t >> 2, dcg = (t & 3) * 16;
  ushort* dst = wbt + ((size_t)w * 1024 + h * 64 + kk) * 1024 + d0 + dcg;
  *(s8vec*)dst       = *(const s8vec*)&T[kk * 72 + dcg];
  *(s8vec*)(dst + 8) = *(const s8vec*)&T[kk * 72 + dcg + 8];
}

// ---- fused QKV projection v16 (round-15 proven, PASSED): 256x192 tile,
// BK=64, 512 thr, 2-phase dbuf, extended bank swizzle, COUNTED-vmcnt (T4):
// vmcnt(7) waits only the previous step's 7 loads; just-issued loads fly
// across the barrier. 0x0F77 = vmcnt(7) expcnt(7) lgkmcnt(15);
// 0x0F70 = vmcnt(0) expcnt(7) lgkmcnt(15). Verified working round 15.
__global__ __launch_bounds__(512) void proj_gemm(const ushort* __restrict__ xb,
                                                 const ushort* __restrict__ wbt,
                                                 ushort* __restrict__ qkv) {
  __shared__ __attribute__((aligned(16))) ushort As[2][256 * 64];
  __shared__ __attribute__((aligned(16))) ushort Bs[2][192 * 64];
  const int tid = threadIdx.x, wid = tid >> 6, lane = tid & 63;
  const int quad = lane >> 4, l15 = lane & 15;
  const int wm = wid & 1, wn = wid >> 1;
  const int m0 = blockIdx.x * 256, n0 = blockIdx.y * 192;

  f4vec acc[8][3];
#pragma unroll
  for (int mb = 0; mb < 8; mb++)
#pragma unroll
    for (int nb = 0; nb < 3; nb++)
#pragma unroll
      for (int i = 0; i < 4; i++) acc[mb][nb][i] = 0.f;

  const int sr = tid >> 3, sg = tid & 7;
  const int gk = sg ^ (sr & 7) ^ ((sr >> 3) & 7);
  const ushort* Ab = xb + (size_t)m0 * D_;
  const ushort* Bb = wbt + (size_t)n0 * D_;

#define PSTAGE(buf, k0_)                                                    \
  do {                                                                      \
    _Pragma("unroll")                                                       \
    for (int j = 0; j < 4; ++j)                                             \
      gl_lds16(Ab + (size_t)(j * 64 + sr) * D_ + (k0_) + gk * 8,            \
               &As[buf][(j * 64 + wid * 8) * 64]);                          \
    _Pragma("unroll")                                                       \
    for (int j = 0; j < 3; ++j)                                             \
      gl_lds16(Bb + (size_t)(j * 64 + sr) * D_ + (k0_) + gk * 8,            \
               &Bs[buf][(j * 64 + wid * 8) * 64]);                          \
  } while (0)

#define PCOMP(buf)                                                          \
  do {                                                                      \
    _Pragma("unroll")                                                       \
    for (int kb = 0; kb < 2; ++kb) {                                        \
      s8vec af[8], bf[3];                                                   \
      _Pragma("unroll")                                                     \
      for (int mb = 0; mb < 8; ++mb) {                                      \
        int m = wm * 128 + mb * 16 + l15;                                   \
        int gpos = (kb * 4 + quad) ^ (m & 7) ^ ((mb * 2 + (l15 >> 3)) & 7); \
        af[mb] = *(const s8vec*)&As[buf][m * 64 + gpos * 8];                \
      }                                                                     \
      _Pragma("unroll")                                                     \
      for (int nb = 0; nb < 3; ++nb) {                                      \
        int n = wn * 48 + nb * 16 + l15;                                    \
        int gpos = (kb * 4 + quad) ^ (n & 7) ^                              \
                   ((wn * 6 + nb * 2 + (l15 >> 3)) & 7);                    \
        bf[nb] = *(const s8vec*)&Bs[buf][n * 64 + gpos * 8];                \
      }                                                                     \
      _Pragma("unroll")                                                     \
      for (int mb = 0; mb < 8; ++mb)                                        \
        _Pragma("unroll")                                                   \
        for (int nb = 0; nb < 3; ++nb)                                      \
          acc[mb][nb] = mfma16(af[mb], bf[nb], acc[mb][nb]);                \
    }                                                                       \
  } while (0)

  PSTAGE(0, 0);
  for (int t = 0; t < 15; ++t) {
    const int cur = t & 1;
    PSTAGE(cur ^ 1, (t + 1) * 64);      // 7 new loads join 7 old in flight
    asm volatile("" ::: "memory");
    __builtin_amdgcn_s_waitcnt(0x0F77); // vmcnt(7): oldest 7 (cur buf) landed
    __builtin_amdgcn_s_barrier();       // all waves' cur-buf loads landed
    asm volatile("" ::: "memory");
    PCOMP(cur);
    asm volatile("" ::: "memory");
    __builtin_amdgcn_s_barrier();       // all reads of cur done before re-stage
    asm volatile("" ::: "memory");
  }
  asm volatile("" ::: "memory");
  __builtin_amdgcn_s_waitcnt(0x0F70);   // vmcnt(0): last tile's loads landed
  __builtin_amdgcn_s_barrier();
  asm volatile("" ::: "memory");
  PCOMP(1);                             // tile 15 (staged in buf 1)
#undef PSTAGE
#undef PCOMP

  const size_t per = (size_t)B_ * H_ * S_ * DK_;
  ushort* vt = qkv + 2 * per;
#pragma unroll
  for (int mb = 0; mb < 8; ++mb)
#pragma unroll
    for (int nb = 0; nb < 3; ++nb) {
      const int n1g = n0 + wn * 48 + nb * 16 + l15;
      const int w = n1g >> 10, n1 = n1g & 1023;
      if (w == 2) {
#pragma unroll
        for (int i = 0; i < 4; ++i) {
          int m = m0 + wm * 128 + mb * 16 + quad * 4 + i;
          int b = m >> 11, s = m & 2047;
          vt[((size_t)b * 1024 + n1) * S_ + s] = f2b(acc[mb][nb][i]);
        }
      } else {
#pragma unroll
        for (int i = 0; i < 4; ++i) {
          int m = m0 + wm * 128 + mb * 16 + quad * 4 + i;
          int b = m >> 11, s = m & 2047;
          qkv[(size_t)w * per + (((size_t)b * H_ + (n1 >> 6)) * S_ + s) * 64 + (n1 & 63)] =
              f2b(acc[mb][nb][i]);
        }
      }
    }
}

// ---- flash attention v17: round-13 structure (fat waves Q-tile 256, 32x32
// MFMA, reg-prefetch, lgkm-only barriers, simple l7 swizzle, XCD remap) +
// LDS DOUBLE-BUFFER: write tile kt+1 into POOL[cur^1] while computing
// POOL[cur] — ONE barrier per tile (was 2; 32 block-wide syncs -> 17).
// Safety: the end-of-iter barrier separates compute(kt) from the write into
// the same buffer two iters later, and publishes write(kt+1) for compute(kt+1).
// Index algebra unchanged (the rounds-11/12 failure was extended-swizzle ×
// reg-prefetch; this keeps the verified l7 swizzle + a buffer offset only).
// Epilogue: ONE-round kh-merge via 64 KB OM aliased over the dead 128 KB pool
// (code from v12, passed).
__global__ __launch_bounds__(512) void attn(const ushort* __restrict__ qg,
                                            const ushort* __restrict__ kg,
                                            const ushort* __restrict__ vtg,
                                            float* __restrict__ out) {
  // POOL[buf]: Ks 128x64 @0, Vt [2 kh][64 dv][64 k] @8192 (32 KB per buf)
  __shared__ __attribute__((aligned(16))) ushort POOL[2][128 * 64 + 2 * 64 * 64];
  __shared__ float LM[4][64];
  float* OM = (float*)POOL;             // epilogue alias: 16 x 1024 f32 = 64 KB

  // XCD-chunked remap: 256 blocks = 8 XCDs x 32; XCD x gets contiguous orig
  // range [x*32, x*32+32) = 4 whole bh. Bijective.
  const int L = blockIdx.x + (blockIdx.y << 3);
  const int orig = (L & 7) * 32 + (L >> 3);
  const int qt = orig & 7, bh = orig >> 3;
  const int b = bh >> 4, h = bh & 15;
  const int tid = threadIdx.x, wid = tid >> 6, lane = tid & 63;
  const int l31 = lane & 31, hi = lane >> 5, l7 = lane & 7;
  const int qgi = wid >> 1, kh = wid & 1;   // q-group 0..3, key-half 0..1

  // Q B-frags: 64 q rows (2 subtiles of 32), 4 d-slices of 16.
  // B layout: col=q=l31, k = s*16 + 8*hi + r.
  const ushort* qb = qg + ((size_t)bh * S_ + qt * 256 + qgi * 64) * DK_;
  s8vec bq[2][4];
#pragma unroll
  for (int qs = 0; qs < 2; ++qs)
#pragma unroll
    for (int s = 0; s < 4; ++s)
      bq[qs][s] = *(const s8vec*)(qb + (size_t)(qs * 32 + l31) * DK_ + s * 16 + hi * 8);

  f16vec o[2][2];           // O^T accum: [dv-half][q-subtile], 32x32 C each
  float lsum[2] = {0.f, 0.f};
#pragma unroll
  for (int dvh = 0; dvh < 2; ++dvh)
#pragma unroll
    for (int qs = 0; qs < 2; ++qs)
#pragma unroll
      for (int i = 0; i < 16; ++i) o[dvh][qs][i] = 0.f;

  // staging: 512 threads stage K 128x64 + V 64x128 per tile (4 loads/thread).
  // LDS[row][gs] = global[row][gs ^ (row&7)]  ((r+64)&7 == r&7).
  const int r6 = tid >> 3, gs = tid & 7;        // r6 0..63, group 0..7
  const int gk = gs ^ (r6 & 7);
  const ushort* kb_ = kg + (size_t)bh * S_ * DK_;
  const ushort* vb_ = vtg + (size_t)bh * 64 * S_ + (size_t)r6 * S_;

  s8vec kr[2], vr[2];
  // tile 0 loads
  kr[0] = *(const s8vec*)(kb_ + (size_t)r6 * DK_ + gk * 8);
  kr[1] = *(const s8vec*)(kb_ + (size_t)(64 + r6) * DK_ + gk * 8);
  vr[0] = *(const s8vec*)(vb_ + gk * 8);
  vr[1] = *(const s8vec*)(vb_ + 64 + gk * 8);
  // prologue: write tile 0 into POOL[0], prefetch tile 1, publish
  {
    ushort* Ksb = POOL[0];
    ushort* Vtb = POOL[0] + 8192;
    *(s8vec*)&Ksb[r6 * 64 + gs * 8]         = kr[0];
    *(s8vec*)&Ksb[(64 + r6) * 64 + gs * 8]  = kr[1];
    *(s8vec*)&Vtb[r6 * 64 + gs * 8]         = vr[0];
    *(s8vec*)&Vtb[4096 + r6 * 64 + gs * 8]  = vr[1];
    const ushort* kn = kb_ + (size_t)128 * DK_;
    kr[0] = *(const s8vec*)(kn + (size_t)r6 * DK_ + gk * 8);
    kr[1] = *(const s8vec*)(kn + (size_t)(64 + r6) * DK_ + gk * 8);
    vr[0] = *(const s8vec*)(vb_ + 128 + gk * 8);
    vr[1] = *(const s8vec*)(vb_ + 128 + 64 + gk * 8);
  }
  wg_barrier_lds();                           // tile-0 staging visible

  for (int kt = 0; kt < S_ / 128; ++kt) {
    const int cur = kt & 1;
    if (kt + 1 < S_ / 128) {
      // write tile kt+1 into the OTHER buffer (its last readers — compute of
      // tile kt-1 — are behind the barrier at the end of iter kt-1)
      ushort* Ksb = POOL[cur ^ 1];
      ushort* Vtb = POOL[cur ^ 1] + 8192;
      *(s8vec*)&Ksb[r6 * 64 + gs * 8]         = kr[0];
      *(s8vec*)&Ksb[(64 + r6) * 64 + gs * 8]  = kr[1];
      *(s8vec*)&Vtb[r6 * 64 + gs * 8]         = vr[0];
      *(s8vec*)&Vtb[4096 + r6 * 64 + gs * 8]  = vr[1];
      if (kt + 2 < S_ / 128) {                // prefetch tile kt+2
        const ushort* kn = kb_ + (size_t)(kt + 2) * 128 * DK_;
        kr[0] = *(const s8vec*)(kn + (size_t)r6 * DK_ + gk * 8);
        kr[1] = *(const s8vec*)(kn + (size_t)(64 + r6) * DK_ + gk * 8);
        const ushort* vn = vb_ + (kt + 2) * 128;
        vr[0] = *(const s8vec*)(vn + gk * 8);
        vr[1] = *(const s8vec*)(vn + 64 + gk * 8);
      }
    }

    const ushort* ksb = POOL[cur];
    const ushort* vtb = POOL[cur] + 8192;
    // this wave: keys [kh*64, kh*64+64) as 2 chunks of 32, for 64 q
#pragma unroll
    for (int c = 0; c < 2; ++c) {
      const int row0 = kh * 64 + c * 32 + l31;    // key row; row0&7 == l7
      s8vec ak[4];
#pragma unroll
      for (int s = 0; s < 4; ++s)
        ak[s] = *(const s8vec*)&ksb[row0 * 64 + (((2 * s + hi)) ^ l7) * 8];

      f16vec st[2];
#pragma unroll
      for (int qs = 0; qs < 2; ++qs)
#pragma unroll
        for (int i = 0; i < 16; ++i) st[qs][i] = 0.f;
#pragma unroll
      for (int s = 0; s < 4; ++s) {
        st[0] = mfma32(ak[s], bq[0][s], st[0]);
        st[1] = mfma32(ak[s], bq[1][s], st[1]);
      }

#pragma unroll
      for (int qs = 0; qs < 2; ++qs) {
        float p[16];
#pragma unroll
        for (int r = 0; r < 16; ++r) p[r] = exp2f_fast(st[qs][r]);
        float s0 = ((p[0] + p[1]) + (p[2] + p[3])) + ((p[4] + p[5]) + (p[6] + p[7]));
        float s1 = ((p[8] + p[9]) + (p[10] + p[11])) + ((p[12] + p[13]) + (p[14] + p[15]));
        lsum[qs] += s0 + s1;
        // per 16-key window m: build PV B-frag (k = 8*hi + 0..7, col = q)
#pragma unroll
        for (int m = 0; m < 2; ++m) {
          unsigned u01 = pk2(p[m * 8 + 0], p[m * 8 + 1]);   // keys {0,1}+4hi
          unsigned u23 = pk2(p[m * 8 + 2], p[m * 8 + 3]);   // keys {2,3}+4hi
          unsigned u89 = pk2(p[m * 8 + 4], p[m * 8 + 5]);   // keys {8,9}+4hi
          unsigned uAB = pk2(p[m * 8 + 6], p[m * 8 + 7]);   // keys {10,11}+4hi
          // swap32: a'=[a.lo|b.lo], b'=[a.hi|b.hi]
          asm("v_permlane32_swap_b32 %0, %1" : "+v"(u01), "+v"(u89));
          asm("v_permlane32_swap_b32 %0, %1" : "+v"(u23), "+v"(uAB));
          union { unsigned u[4]; s8vec v; } pb;
          pb.u[0] = u01;   // w0: [{0,1}|{8,9}]
          pb.u[1] = u23;   // w1: [{2,3}|{10,11}]
          pb.u[2] = u89;   // w2: [{4,5}|{12,13}]
          pb.u[3] = uAB;   // w3: [{6,7}|{14,15}]
#pragma unroll
          for (int dvh = 0; dvh < 2; ++dvh) {
            s8vec av = *(const s8vec*)&vtb[kh * 4096 + (dvh * 32 + l31) * 64 +
                                           ((4 * c + 2 * m + hi) ^ l7) * 8];
            o[dvh][qs] = mfma32(av, pb.v, o[dvh][qs]);
          }
        }
      }
    }
    wg_barrier_lds();   // compute(kt) done (readers of POOL[cur] released);
                        // write(kt+1) published for compute(kt+1)
  }

  // per-q partial sum over this wave's key-half (hi-halves hold disjoint keys)
#pragma unroll
  for (int qs = 0; qs < 2; ++qs) lsum[qs] += __shfl_xor(lsum[qs], 32, 64);

  // merge kh pair in ONE round (v12's verified epilogue): kh=1 publishes into
  // OM (64 KB alias over dead POOL); kh=0 combines + normalizes + writes.
  if (kh == 1) {
#pragma unroll
    for (int dvh = 0; dvh < 2; ++dvh)
#pragma unroll
      for (int qs = 0; qs < 2; ++qs)
#pragma unroll
        for (int r = 0; r < 16; ++r)
          OM[(qgi * 4 + dvh * 2 + qs) * 1024 + r * 64 + lane] = o[dvh][qs][r];
    if (!hi) {
      LM[qgi][l31]      = lsum[0];
      LM[qgi][32 + l31] = lsum[1];
    }
  }
  __syncthreads();
  if (kh == 0) {
    float linv[2];
#pragma unroll
    for (int qs = 0; qs < 2; ++qs)
      linv[qs] = 1.0f / (lsum[qs] + LM[qgi][qs * 32 + l31]);
    float* ob = out + ((size_t)b * S_ + qt * 256 + qgi * 64) * D_ + h * DK_;
#pragma unroll
    for (int dvh = 0; dvh < 2; ++dvh)
#pragma unroll
      for (int qs = 0; qs < 2; ++qs)
#pragma unroll
        for (int qd = 0; qd < 4; ++qd) {
          const int slot = (qgi * 4 + dvh * 2 + qs) * 1024;
          float4 vv;
          vv.x = (o[dvh][qs][qd * 4 + 0] + OM[slot + (qd * 4 + 0) * 64 + lane]) * linv[qs];
          vv.y = (o[dvh][qs][qd * 4 + 1] + OM[slot + (qd * 4 + 1) * 64 + lane]) * linv[qs];
          vv.z = (o[dvh][qs][qd * 4 + 2] + OM[slot + (qd * 4 + 2) * 64 + lane]) * linv[qs];
          vv.w = (o[dvh][qs][qd * 4 + 3] + OM[slot + (qd * 4 + 3) * 64 + lane]) * linv[qs];
          // dv = dvh*32 + qd*8 + 4*hi + {0..3}
          *(float4*)&ob[(size_t)(qs * 32 + l31) * D_ + dvh * 32 + qd * 8 + 4 * hi] = vv;
        }
  }
}

extern "C" void kernel_launch(void* const* d_in, const int* in_sizes, int n_in,
                              void* d_out, int out_size, void* d_ws, size_t ws_size,
                              hipStream_t stream) {
  const float* x  = (const float*)d_in[0];
  const float* Wq = (const float*)d_in[1];
  const float* Wk = (const float*)d_in[2];
  const float* Wv = (const float*)d_in[3];
  float* out = (float*)d_out;

  ushort* xb  = (ushort*)d_ws;                       // B*S*D bf16
  ushort* wbt = xb + (size_t)B_ * S_ * D_;           // [3072][1024] bf16
  ushort* qkv = wbt + (size_t)3 * D_ * D_;           // q,k: [b][h][s][64]; v: [b*1024+n1][s]
  const size_t per = (size_t)B_ * H_ * S_ * DK_;

  cvt_xw<<<4096 + 768, 256, 0, stream>>>(x, Wq, Wk, Wv, xb, wbt);
  proj_gemm<<<dim3(M_ / 256, N_ / 192), 512, 0, stream>>>(xb, wbt, qkv);
  attn<<<dim3(S_ / 256, B_ * H_), 512, 0, stream>>>(qkv, qkv + per, qkv + 2 * per, out);
}